// Round 14
// baseline (301.678 us; speedup 1.0000x reference)
//
#include <hip/hip_runtime.h>

// ---------------------------------------------------------------------------
// 3-layer GCN forward. out[d] = relu( dinv[d]*( sum_{s->d} g[s] + g[d] ) + b ),
// g = (x@W)*dinv stored as OCP fp8 e4m3 scaled by S=256.
// r14: (1) layer-1 message table sliced [2][N][32] (3.2MB/slice fits per-XCD
// L2); agg1 runs 2 stream-serialized dispatches so one slice is hot at a
// time -> gathers become L2 hits. (2) inter-layer activations Xb in bf16
// (agg writes bf16, mfma2/3 read bf16 A directly, no cvt).
// k_mfma: barrier-free direct-A (r13). k_agg: r10 shape, fp8 payload (r12).
// CSR: two-level counting sort (bucket = dst>>9), LDS-reordered partition.
// ---------------------------------------------------------------------------

#define BSH 9                 // 512 nodes per bucket
#define BNODES (1 << BSH)
#define FP8_S 256.0f          // message scale (e4m3: denorm<0.0156, max 448)

typedef __attribute__((ext_vector_type(8))) short bf16x8;
typedef __attribute__((ext_vector_type(4))) float f32x4;
typedef __attribute__((ext_vector_type(2))) float f32x2;

__device__ inline ushort f2bf(float x) {   // round-to-nearest-even f32->bf16
    uint u = __float_as_uint(x);
    return (ushort)((u + 0x7fffu + ((u >> 16) & 1u)) >> 16);
}
__device__ inline float bf2f(ushort h) { return __uint_as_float(((uint)h) << 16); }
__device__ inline void split2(float x, ushort& h, ushort& l) {
    ushort hh = f2bf(x);
    h = hh;
    l = f2bf(x - bf2f(hh));
}
__device__ inline unsigned char f2fp8(float v) {   // f32 -> e4m3 (HW, RNE+sat)
    int p = __builtin_amdgcn_cvt_pk_fp8_f32(v, v, 0, false);
    return (unsigned char)(p & 0xff);
}

// fused: bucket histogram of dst (blocks < HB) + W1/W2/W3 split/transpose
__global__ __launch_bounds__(256) void k_pre(
    const int* __restrict__ dst, int* __restrict__ bcnt, int E, int HB,
    const float* __restrict__ W1, const float* __restrict__ W2,
    const float* __restrict__ W3,
    ushort* __restrict__ Wh1, ushort* __restrict__ Wh2,
    ushort* __restrict__ Wh3)
{
    if ((int)blockIdx.x < HB) {
        __shared__ int h[256];
        int t = threadIdx.x;
        h[t] = 0;
        __syncthreads();
        for (int i = blockIdx.x * 256 + t; i < E; i += HB * 256)
            atomicAdd(&h[dst[i] >> BSH], 1);
        __syncthreads();
        if (h[t]) atomicAdd(&bcnt[t], h[t]);
        return;
    }
    int i = (blockIdx.x - HB) * 256 + threadIdx.x;
    if (i < 16384) {                       // W1: 256x64
        int k = i >> 6, n = i & 63;
        Wh1[n * 256 + k] = f2bf(W1[i]);
    } else if (i < 16384 + 2048) {         // W2: 64x32
        int j = i - 16384;
        int k = j >> 5, n = j & 31;
        Wh2[n * 64 + k] = f2bf(W2[j]);
    } else if (i < 16384 + 2048 + 512) {   // W3: 32x16
        int j = i - 18432;
        int k = j >> 4, n = j & 15;
        Wh3[n * 32 + k] = f2bf(W3[j]);
    }
}

// scan bucket counts -> boff (exclusive), init bcur. NB <= 1024.
__global__ __launch_bounds__(1024) void k_bscan(const int* __restrict__ bcnt,
                                                int* __restrict__ boff,
                                                int* __restrict__ bcur, int NB) {
    __shared__ int s[1024];
    int t = threadIdx.x;
    int v = (t < NB) ? bcnt[t] : 0;
    s[t] = v;
    __syncthreads();
    for (int off = 1; off < 1024; off <<= 1) {
        int a = (t >= off) ? s[t - off] : 0;
        __syncthreads();
        s[t] += a;
        __syncthreads();
    }
    if (t < NB) {
        int ex = s[t] - v;
        boff[t] = ex;
        bcur[t] = ex;
    }
    if (t == NB - 1) boff[NB] = s[t];
}

// partition edges into bucket-contiguous packed (local_dst<<23 | src) words.
// LDS reorder: bin chunk bucket-major, write coalesced runs (no 4x write amp).
template <int CH>
__global__ __launch_bounds__(256) void k_part(const int* __restrict__ src,
                                              const int* __restrict__ dst,
                                              int* __restrict__ bcur,
                                              uint* __restrict__ pairs,
                                              int E, int NB) {
    __shared__ uint sval[CH];
    __shared__ unsigned char sbid[CH];     // NB <= 256
    __shared__ int lh[256], lofs[256], lbase[256], cur[256];
    const int t = threadIdx.x;
    const int e0 = blockIdx.x * CH;
    const int n = min(CH, E - e0);

    lh[t] = 0;
    cur[t] = 0;
    __syncthreads();
    for (int i = t; i < n; i += 256) atomicAdd(&lh[dst[e0 + i] >> BSH], 1);
    __syncthreads();
    int v = lh[t];
    lofs[t] = v;
    __syncthreads();
    for (int off = 1; off < 256; off <<= 1) {
        int a = (t >= off) ? lofs[t - off] : 0;
        __syncthreads();
        lofs[t] += a;
        __syncthreads();
    }
    int ex = lofs[t] - v;
    if (v > 0) lbase[t] = atomicAdd(&bcur[t], v);
    __syncthreads();
    lofs[t] = ex;
    __syncthreads();
    for (int i = t; i < n; i += 256) {
        int d = dst[e0 + i];
        int b = d >> BSH;
        int r = atomicAdd(&cur[b], 1);
        int slot = lofs[b] + r;
        sval[slot] = ((uint)(d & (BNODES - 1)) << 23) | (uint)src[e0 + i];
        sbid[slot] = (unsigned char)b;
    }
    __syncthreads();
    for (int i = t; i < n; i += 256) {
        int b = sbid[i];
        pairs[(long)lbase[b] + (i - lofs[b])] = sval[i];
    }
}

// per-bucket: per-node histogram + scan (LDS), emit row_off/dinv, scatter esrc
__global__ __launch_bounds__(1024) void k_bucket(const uint* __restrict__ pairs,
                                                 const int* __restrict__ boff,
                                                 int* __restrict__ row_off,
                                                 float* __restrict__ dinv,
                                                 int* __restrict__ esrc,
                                                 int N, int NB, int E) {
    __shared__ int cnt[BNODES];
    __shared__ int sc[BNODES];
    __shared__ int cur[BNODES];
    const int b = blockIdx.x;
    const int t = threadIdx.x;
    const int base = b << BSH;
    const int nn = min(BNODES, N - base);
    const int ebase = boff[b], eend = boff[b + 1];

    if (t < BNODES) cnt[t] = 0;
    __syncthreads();
    for (int e = ebase + t; e < eend; e += 1024)
        atomicAdd(&cnt[pairs[e] >> 23], 1);
    __syncthreads();
    if (t < BNODES) sc[t] = cnt[t];
    __syncthreads();
    for (int off = 1; off < BNODES; off <<= 1) {
        int a = (t < BNODES && t >= off) ? sc[t - off] : 0;
        __syncthreads();
        if (t < BNODES) sc[t] += a;
        __syncthreads();
    }
    if (t < nn) {
        int ex = sc[t] - cnt[t];
        row_off[base + t] = ebase + ex;
        cur[t] = ex;
        dinv[base + t] = rsqrtf((float)(cnt[t] + 1));
    }
    if (b == NB - 1 && t == 0) row_off[N] = E;
    __syncthreads();
    for (int e = ebase + t; e < eend; e += 1024) {
        uint p = pairs[e];
        int r = atomicAdd(&cur[p >> 23], 1);
        esrc[ebase + r] = (int)(p & 0x7fffffu);
    }
}

// ---------------------------------------------------------------------------
// Barrier-free direct-A MFMA GEMM (single-pass bf16):
// G = fp8( (X[row(n)] @ W) * dinv[n] * S ).
// XBF16: X is bf16 stride-sx (load fragment directly, no cvt).
// SLICED: write [2][N][32] slice layout (slice = nt>>1) instead of [N][OF].
// Block = 64 rows (4 waves x 16), W in LDS [OF][K+8] staged once.
// ---------------------------------------------------------------------------
template <int K, int OF, bool XBF16, bool SLICED>
__global__ __launch_bounds__(256) void k_mfma(
    const void* __restrict__ Xv, int sx,
    const int* __restrict__ nodes,          // may be null (identity)
    const ushort* __restrict__ Wh,          // [OF][K] bf16
    const float* __restrict__ dinv,
    unsigned char* __restrict__ G,          // fp8 e4m3, value*S
    int N)
{
    constexpr int LDK = K + 8;
    constexpr int NT = OF / 16;             // MFMA col tiles
    constexpr int NSTEP = K / 32;
    __shared__ ushort Wlds[OF * LDK];

    const int tid = threadIdx.x;
    const int l = tid & 63;
    const int w = tid >> 6;                 // wave id: rows w*16..w*16+15
    const int m0 = blockIdx.x * 64;
    const int lm = l & 15, kg = l >> 4;

#pragma unroll
    for (int i = tid; i < OF * K / 8; i += 256) {
        int n = i / (K / 8), seg = i % (K / 8);
        *reinterpret_cast<uint4*>(&Wlds[n * LDK + seg * 8]) =
            *reinterpret_cast<const uint4*>(Wh + (long)n * K + seg * 8);
    }

    const float* xrf = nullptr;
    const ushort* xrb = nullptr;
    {
        int m = m0 + w * 16 + lm;
        if (m < N) {
            long r = nodes ? (long)nodes[m] : (long)m;
            if (XBF16) xrb = (const ushort*)Xv + r * (long)sx + kg * 8;
            else       xrf = (const float*)Xv + r * (long)sx + kg * 8;
        }
    }

    f32x4 acc[NT];
#pragma unroll
    for (int nt = 0; nt < NT; ++nt) acc[nt] = (f32x4){0.f, 0.f, 0.f, 0.f};

    __syncthreads();   // W staged; K-loop below is barrier-free

#pragma unroll
    for (int s = 0; s < NSTEP; ++s) {
        bf16x8 av = (bf16x8){0, 0, 0, 0, 0, 0, 0, 0};
        if (XBF16) {
            if (xrb) av = *reinterpret_cast<const bf16x8*>(xrb + s * 32);
        } else if (xrf) {
            float4 a0 = *reinterpret_cast<const float4*>(xrf + s * 32);
            float4 a1 = *reinterpret_cast<const float4*>(xrf + s * 32 + 4);
            av[0] = (short)f2bf(a0.x); av[1] = (short)f2bf(a0.y);
            av[2] = (short)f2bf(a0.z); av[3] = (short)f2bf(a0.w);
            av[4] = (short)f2bf(a1.x); av[5] = (short)f2bf(a1.y);
            av[6] = (short)f2bf(a1.z); av[7] = (short)f2bf(a1.w);
        }
#pragma unroll
        for (int nt = 0; nt < NT; ++nt) {
            bf16x8 bv = *reinterpret_cast<bf16x8*>(
                &Wlds[(nt * 16 + lm) * LDK + s * 32 + kg * 8]);
            acc[nt] = __builtin_amdgcn_mfma_f32_16x16x32_bf16(av, bv, acc[nt], 0, 0, 0);
        }
    }

#pragma unroll
    for (int r = 0; r < 4; ++r) {
        int m = m0 + w * 16 + kg * 4 + r;
        if (m < N) {
            float sc = dinv[m] * FP8_S;
#pragma unroll
            for (int nt = 0; nt < NT; ++nt) {
                unsigned char v = f2fp8(acc[nt][r] * sc);
                if (SLICED)
                    G[(long)(nt >> 1) * N * 32 + (long)m * 32 + (nt & 1) * 16 + lm] = v;
                else
                    G[(long)m * OF + nt * 16 + lm] = v;
            }
        }
    }
}

// ---------------------------------------------------------------------------
// CSR aggregation — r10 shape, fp8 payload. One wave per node; OF/4 lanes per
// edge, each lane one uint (4 e4m3); 8 gathers in flight (two 4-packs),
// 4 accumulator sets; f32 accumulate via HW cvt_pk; epilogue folds 1/S.
// YBF16: write activations as bf16 (next layer reads bf16 A directly).
// ---------------------------------------------------------------------------
#define UNPK4(A, W)                                                        \
    {                                                                      \
        f32x2 _lo = __builtin_amdgcn_cvt_pk_f32_fp8((int)(W), false);      \
        f32x2 _hi = __builtin_amdgcn_cvt_pk_f32_fp8((int)(W), true);       \
        A.x += _lo[0]; A.y += _lo[1]; A.z += _hi[0]; A.w += _hi[1];        \
    }

template <int OF, int OSTRIDE, bool YBF16>
__global__ __launch_bounds__(256) void k_agg(
    const int* __restrict__ row_off, const int* __restrict__ esrc,
    const uint* __restrict__ g,      // table row = OF/4 uints (OF fp8 bytes)
    const float* __restrict__ dinv, const float* __restrict__ b,
    void* __restrict__ y, int N)
{
    constexpr int WPE = OF / 4;      // lanes per edge
    constexpr int EPW = 64 / WPE;    // edges in parallel
    const int lane = threadIdx.x & 63;
    const int q = lane % WPE;        // feature quad
    const int sub = lane / WPE;
    const int n = blockIdx.x * (blockDim.x >> 6) + (threadIdx.x >> 6);
    if (n >= N) return;
    const int start = row_off[n], end = row_off[n + 1];

    float4 ac[4];
#pragma unroll
    for (int u = 0; u < 4; ++u) ac[u] = make_float4(0.f, 0.f, 0.f, 0.f);

    int e = start + sub;
    for (; e + 7 * EPW < end; e += 8 * EPW) {
        int s0[4], s1[4];
#pragma unroll
        for (int u = 0; u < 4; ++u) s0[u] = esrc[e + u * EPW];
#pragma unroll
        for (int u = 0; u < 4; ++u) s1[u] = esrc[e + (4 + u) * EPW];
        uint w0[4], w1[4];
#pragma unroll
        for (int u = 0; u < 4; ++u) w0[u] = g[(long)s0[u] * WPE + q];
#pragma unroll
        for (int u = 0; u < 4; ++u) w1[u] = g[(long)s1[u] * WPE + q];
#pragma unroll
        for (int u = 0; u < 4; ++u) { UNPK4(ac[u], w0[u]); }
#pragma unroll
        for (int u = 0; u < 4; ++u) { UNPK4(ac[u], w1[u]); }
    }
    for (; e + 3 * EPW < end; e += 4 * EPW) {
        int s[4];
        uint w[4];
#pragma unroll
        for (int u = 0; u < 4; ++u) s[u] = esrc[e + u * EPW];
#pragma unroll
        for (int u = 0; u < 4; ++u) w[u] = g[(long)s[u] * WPE + q];
#pragma unroll
        for (int u = 0; u < 4; ++u) { UNPK4(ac[u], w[u]); }
    }
    for (; e < end; e += EPW) {
        uint w = g[(long)esrc[e] * WPE + q];
        UNPK4(ac[0], w);
    }
    float4 a;
    a.x = (ac[0].x + ac[1].x) + (ac[2].x + ac[3].x);
    a.y = (ac[0].y + ac[1].y) + (ac[2].y + ac[3].y);
    a.z = (ac[0].z + ac[1].z) + (ac[2].z + ac[3].z);
    a.w = (ac[0].w + ac[1].w) + (ac[2].w + ac[3].w);
#pragma unroll
    for (int m = WPE; m < 64; m <<= 1) {
        a.x += __shfl_xor(a.x, m, 64);
        a.y += __shfl_xor(a.y, m, 64);
        a.z += __shfl_xor(a.z, m, 64);
        a.w += __shfl_xor(a.w, m, 64);
    }
    if (sub == 0) {
        uint sv = g[(long)n * WPE + q];   // self loop
        UNPK4(a, sv);
        float dvs = dinv[n] * (1.0f / FP8_S);
        float4 bb = *reinterpret_cast<const float4*>(&b[q * 4]);
        float4 o;
        o.x = fmaxf(fmaf(a.x, dvs, bb.x), 0.f);
        o.y = fmaxf(fmaf(a.y, dvs, bb.y), 0.f);
        o.z = fmaxf(fmaf(a.z, dvs, bb.z), 0.f);
        o.w = fmaxf(fmaf(a.w, dvs, bb.w), 0.f);
        if (YBF16) {
            ushort4 ob = {f2bf(o.x), f2bf(o.y), f2bf(o.z), f2bf(o.w)};
            *reinterpret_cast<ushort4*>((ushort*)y + (long)n * OSTRIDE + q * 4) = ob;
        } else {
            *reinterpret_cast<float4*>((float*)y + (long)n * OSTRIDE + q * 4) = o;
        }
    }
}

extern "C" void kernel_launch(void* const* d_in, const int* in_sizes, int n_in,
                              void* d_out, int out_size, void* d_ws, size_t ws_size,
                              hipStream_t stream) {
    const int*   nodes = (const int*)d_in[0];
    const int*   edges = (const int*)d_in[1];
    const float* emb   = (const float*)d_in[2];
    const float* W1    = (const float*)d_in[3];
    const float* b1    = (const float*)d_in[4];
    const float* W2    = (const float*)d_in[5];
    const float* b2    = (const float*)d_in[6];
    const float* W3    = (const float*)d_in[7];
    const float* b3    = (const float*)d_in[8];

    const int N = in_sizes[0];
    const int E = in_sizes[1] / 2;
    const int* src  = edges;
    const int* dstv = edges + E;
    const int NB = (N + BNODES - 1) >> BSH;   // 196 for N=100000

    char* ws = (char*)d_ws;
    size_t off = 0;
    auto alloc = [&](size_t bytes) {
        char* p = ws + off;
        off += (bytes + 255) & ~(size_t)255;
        return p;
    };
    float* dinv    = (float*)alloc((size_t)N * 4);
    int*   row_off = (int*)  alloc((size_t)(N + 1) * 4);
    int*   bcnt    = (int*)  alloc((size_t)(NB + 1) * 4);
    int*   boff    = (int*)  alloc((size_t)(NB + 1) * 4);
    int*   bcur    = (int*)  alloc((size_t)NB * 4);
    int*   esrc    = (int*)  alloc((size_t)E * 4);
    char*  shared_region = alloc((size_t)E * 4);   // pairs u32 (12.8MB) / G1 fp8 (6.4MB)
    uint*  pairs   = (uint*)shared_region;
    unsigned char* G1 = (unsigned char*)shared_region;   // [2][N][32] fp8 slices
    unsigned char* G2 = (unsigned char*)alloc((size_t)N * 32);
    unsigned char* G3 = (unsigned char*)alloc((size_t)N * 16);
    ushort* Xb     = (ushort*)alloc((size_t)N * 64 * 2);  // bf16 activations
    ushort* Wh1 = (ushort*)alloc(16384 * 2);
    ushort* Wh2 = (ushort*)alloc(2048 * 2);
    ushort* Wh3 = (ushort*)alloc(512 * 2);
    float* out     = (float*)d_out;

    // --- CSR build + dinv + W prep ---
    constexpr int CH = 8192;
    constexpr int HB = 1024;              // histogram blocks in k_pre
    const int nch = (E + CH - 1) / CH;
    hipMemsetAsync(bcnt, 0, (size_t)NB * 4, stream);
    hipLaunchKernelGGL(k_pre, dim3(HB + 74), dim3(256), 0, stream,
                       dstv, bcnt, E, HB, W1, W2, W3, Wh1, Wh2, Wh3);
    hipLaunchKernelGGL(k_bscan,  dim3(1), dim3(1024), 0, stream, bcnt, boff, bcur, NB);
    hipLaunchKernelGGL((k_part<CH>), dim3(nch), dim3(256), 0, stream,
                       src, dstv, bcur, pairs, E, NB);
    hipLaunchKernelGGL(k_bucket, dim3(NB), dim3(1024), 0, stream,
                       pairs, boff, row_off, dinv, esrc, N, NB, E);

    const int gb = (N + 63) / 64;
    const int ab = (N + 3) / 4;   // 4 waves / block

    // --- layer 1: 256 -> 64 ---  (G1 overwrites pairs; dead after k_bucket)
    hipLaunchKernelGGL((k_mfma<256, 64, false, true>), dim3(gb), dim3(256), 0, stream,
                       emb, 256, nodes, Wh1, dinv, G1, N);
    // agg1: 2 slice dispatches; each slice table 3.2MB -> per-XCD L2-resident
    for (int sl = 0; sl < 2; ++sl)
        hipLaunchKernelGGL((k_agg<32, 64, true>), dim3(ab), dim3(256), 0, stream,
                           row_off, esrc,
                           (const uint*)(G1 + (size_t)sl * N * 32),
                           dinv, b1 + sl * 32, Xb + sl * 32, N);
    // --- layer 2: 64 -> 32 ---
    hipLaunchKernelGGL((k_mfma<64, 32, true, false>), dim3(gb), dim3(256), 0, stream,
                       Xb, 64, (const int*)nullptr, Wh2, dinv, G2, N);
    hipLaunchKernelGGL((k_agg<32, 64, true>), dim3(ab), dim3(256), 0, stream,
                       row_off, esrc, (const uint*)G2, dinv, b2, Xb, N);
    // --- layer 3: 32 -> 16 ---
    hipLaunchKernelGGL((k_mfma<32, 16, true, false>), dim3(gb), dim3(256), 0, stream,
                       Xb, 64, (const int*)nullptr, Wh3, dinv, G3, N);
    hipLaunchKernelGGL((k_agg<16, 16, false>), dim3(ab), dim3(256), 0, stream,
                       row_off, esrc, (const uint*)G3, dinv, b3, out, N);
}

// Round 16
// 241.642 us; speedup vs baseline: 1.2485x; 1.2485x over previous
//
#include <hip/hip_runtime.h>

// ---------------------------------------------------------------------------
// 3-layer GCN forward. out[d] = relu( dinv[d]*( sum_{s->d} g[s] + g[d] ) + b ),
// g = (x@W)*dinv stored as OCP fp8 e4m3 scaled by S=256, row-major [N][OF].
// r15: slice reverted (r14: OF=32 pass halved per-wave MLP 8->4 -> regression).
// k_agg generalized to NPW nodes/wave so EVERY layer runs EPW=4 => one full
// 8-deep gather pipeline at deg~32: agg1 NPW=1 (r13 shape), agg2 NPW=2,
// agg3 NPW=4 (was 1-deep tail x2!). Xb activations bf16 (accuracy-neutral,
// verified r14: absmax identical).
// k_mfma: barrier-free direct-A (r13). CSR: two-level counting sort (r10).
// ---------------------------------------------------------------------------

#define BSH 9                 // 512 nodes per bucket
#define BNODES (1 << BSH)
#define FP8_S 256.0f          // message scale (e4m3: denorm<0.0156, max 448)

typedef __attribute__((ext_vector_type(8))) short bf16x8;
typedef __attribute__((ext_vector_type(4))) float f32x4;
typedef __attribute__((ext_vector_type(2))) float f32x2;

__device__ inline ushort f2bf(float x) {   // round-to-nearest-even f32->bf16
    uint u = __float_as_uint(x);
    return (ushort)((u + 0x7fffu + ((u >> 16) & 1u)) >> 16);
}
__device__ inline unsigned char f2fp8(float v) {   // f32 -> e4m3 (HW, RNE+sat)
    int p = __builtin_amdgcn_cvt_pk_fp8_f32(v, v, 0, false);
    return (unsigned char)(p & 0xff);
}

// fused: bucket histogram of dst (blocks < HB) + W1/W2/W3 bf16 transpose
__global__ __launch_bounds__(256) void k_pre(
    const int* __restrict__ dst, int* __restrict__ bcnt, int E, int HB,
    const float* __restrict__ W1, const float* __restrict__ W2,
    const float* __restrict__ W3,
    ushort* __restrict__ Wh1, ushort* __restrict__ Wh2,
    ushort* __restrict__ Wh3)
{
    if ((int)blockIdx.x < HB) {
        __shared__ int h[256];
        int t = threadIdx.x;
        h[t] = 0;
        __syncthreads();
        for (int i = blockIdx.x * 256 + t; i < E; i += HB * 256)
            atomicAdd(&h[dst[i] >> BSH], 1);
        __syncthreads();
        if (h[t]) atomicAdd(&bcnt[t], h[t]);
        return;
    }
    int i = (blockIdx.x - HB) * 256 + threadIdx.x;
    if (i < 16384) {                       // W1: 256x64
        int k = i >> 6, n = i & 63;
        Wh1[n * 256 + k] = f2bf(W1[i]);
    } else if (i < 16384 + 2048) {         // W2: 64x32
        int j = i - 16384;
        int k = j >> 5, n = j & 31;
        Wh2[n * 64 + k] = f2bf(W2[j]);
    } else if (i < 16384 + 2048 + 512) {   // W3: 32x16
        int j = i - 18432;
        int k = j >> 4, n = j & 15;
        Wh3[n * 32 + k] = f2bf(W3[j]);
    }
}

// scan bucket counts -> boff (exclusive), init bcur. NB <= 1024.
__global__ __launch_bounds__(1024) void k_bscan(const int* __restrict__ bcnt,
                                                int* __restrict__ boff,
                                                int* __restrict__ bcur, int NB) {
    __shared__ int s[1024];
    int t = threadIdx.x;
    int v = (t < NB) ? bcnt[t] : 0;
    s[t] = v;
    __syncthreads();
    for (int off = 1; off < 1024; off <<= 1) {
        int a = (t >= off) ? s[t - off] : 0;
        __syncthreads();
        s[t] += a;
        __syncthreads();
    }
    if (t < NB) {
        int ex = s[t] - v;
        boff[t] = ex;
        bcur[t] = ex;
    }
    if (t == NB - 1) boff[NB] = s[t];
}

// partition edges into bucket-contiguous packed (local_dst<<23 | src) words.
// LDS reorder: bin chunk bucket-major, write coalesced runs (no 4x write amp).
template <int CH>
__global__ __launch_bounds__(256) void k_part(const int* __restrict__ src,
                                              const int* __restrict__ dst,
                                              int* __restrict__ bcur,
                                              uint* __restrict__ pairs,
                                              int E, int NB) {
    __shared__ uint sval[CH];
    __shared__ unsigned char sbid[CH];     // NB <= 256
    __shared__ int lh[256], lofs[256], lbase[256], cur[256];
    const int t = threadIdx.x;
    const int e0 = blockIdx.x * CH;
    const int n = min(CH, E - e0);

    lh[t] = 0;
    cur[t] = 0;
    __syncthreads();
    for (int i = t; i < n; i += 256) atomicAdd(&lh[dst[e0 + i] >> BSH], 1);
    __syncthreads();
    int v = lh[t];
    lofs[t] = v;
    __syncthreads();
    for (int off = 1; off < 256; off <<= 1) {
        int a = (t >= off) ? lofs[t - off] : 0;
        __syncthreads();
        lofs[t] += a;
        __syncthreads();
    }
    int ex = lofs[t] - v;
    if (v > 0) lbase[t] = atomicAdd(&bcur[t], v);
    __syncthreads();
    lofs[t] = ex;
    __syncthreads();
    for (int i = t; i < n; i += 256) {
        int d = dst[e0 + i];
        int b = d >> BSH;
        int r = atomicAdd(&cur[b], 1);
        int slot = lofs[b] + r;
        sval[slot] = ((uint)(d & (BNODES - 1)) << 23) | (uint)src[e0 + i];
        sbid[slot] = (unsigned char)b;
    }
    __syncthreads();
    for (int i = t; i < n; i += 256) {
        int b = sbid[i];
        pairs[(long)lbase[b] + (i - lofs[b])] = sval[i];
    }
}

// per-bucket: per-node histogram + scan (LDS), emit row_off/dinv, scatter esrc
__global__ __launch_bounds__(1024) void k_bucket(const uint* __restrict__ pairs,
                                                 const int* __restrict__ boff,
                                                 int* __restrict__ row_off,
                                                 float* __restrict__ dinv,
                                                 int* __restrict__ esrc,
                                                 int N, int NB, int E) {
    __shared__ int cnt[BNODES];
    __shared__ int sc[BNODES];
    __shared__ int cur[BNODES];
    const int b = blockIdx.x;
    const int t = threadIdx.x;
    const int base = b << BSH;
    const int nn = min(BNODES, N - base);
    const int ebase = boff[b], eend = boff[b + 1];

    if (t < BNODES) cnt[t] = 0;
    __syncthreads();
    for (int e = ebase + t; e < eend; e += 1024)
        atomicAdd(&cnt[pairs[e] >> 23], 1);
    __syncthreads();
    if (t < BNODES) sc[t] = cnt[t];
    __syncthreads();
    for (int off = 1; off < BNODES; off <<= 1) {
        int a = (t < BNODES && t >= off) ? sc[t - off] : 0;
        __syncthreads();
        if (t < BNODES) sc[t] += a;
        __syncthreads();
    }
    if (t < nn) {
        int ex = sc[t] - cnt[t];
        row_off[base + t] = ebase + ex;
        cur[t] = ex;
        dinv[base + t] = rsqrtf((float)(cnt[t] + 1));
    }
    if (b == NB - 1 && t == 0) row_off[N] = E;
    __syncthreads();
    for (int e = ebase + t; e < eend; e += 1024) {
        uint p = pairs[e];
        int r = atomicAdd(&cur[p >> 23], 1);
        esrc[ebase + r] = (int)(p & 0x7fffffu);
    }
}

// ---------------------------------------------------------------------------
// Barrier-free direct-A MFMA GEMM (single-pass bf16):
// G[n][0..OF) = fp8( (X[row(n)] @ W) * dinv[n] * S ), row-major stride OF.
// XBF16: X is bf16 stride-sx (load fragment directly, no cvt).
// Block = 64 rows (4 waves x 16), W in LDS [OF][K+8] staged once.
// ---------------------------------------------------------------------------
template <int K, int OF, bool XBF16>
__global__ __launch_bounds__(256) void k_mfma(
    const void* __restrict__ Xv, int sx,
    const int* __restrict__ nodes,          // may be null (identity)
    const ushort* __restrict__ Wh,          // [OF][K] bf16
    const float* __restrict__ dinv,
    unsigned char* __restrict__ G,          // fp8 e4m3, stride OF, value*S
    int N)
{
    constexpr int LDK = K + 8;
    constexpr int NT = OF / 16;             // MFMA col tiles
    constexpr int NSTEP = K / 32;
    __shared__ ushort Wlds[OF * LDK];

    const int tid = threadIdx.x;
    const int l = tid & 63;
    const int w = tid >> 6;                 // wave id: rows w*16..w*16+15
    const int m0 = blockIdx.x * 64;
    const int lm = l & 15, kg = l >> 4;

#pragma unroll
    for (int i = tid; i < OF * K / 8; i += 256) {
        int n = i / (K / 8), seg = i % (K / 8);
        *reinterpret_cast<uint4*>(&Wlds[n * LDK + seg * 8]) =
            *reinterpret_cast<const uint4*>(Wh + (long)n * K + seg * 8);
    }

    const float* xrf = nullptr;
    const ushort* xrb = nullptr;
    {
        int m = m0 + w * 16 + lm;
        if (m < N) {
            long r = nodes ? (long)nodes[m] : (long)m;
            if (XBF16) xrb = (const ushort*)Xv + r * (long)sx + kg * 8;
            else       xrf = (const float*)Xv + r * (long)sx + kg * 8;
        }
    }

    f32x4 acc[NT];
#pragma unroll
    for (int nt = 0; nt < NT; ++nt) acc[nt] = (f32x4){0.f, 0.f, 0.f, 0.f};

    __syncthreads();   // W staged; K-loop below is barrier-free

#pragma unroll
    for (int s = 0; s < NSTEP; ++s) {
        bf16x8 av = (bf16x8){0, 0, 0, 0, 0, 0, 0, 0};
        if (XBF16) {
            if (xrb) av = *reinterpret_cast<const bf16x8*>(xrb + s * 32);
        } else if (xrf) {
            float4 a0 = *reinterpret_cast<const float4*>(xrf + s * 32);
            float4 a1 = *reinterpret_cast<const float4*>(xrf + s * 32 + 4);
            av[0] = (short)f2bf(a0.x); av[1] = (short)f2bf(a0.y);
            av[2] = (short)f2bf(a0.z); av[3] = (short)f2bf(a0.w);
            av[4] = (short)f2bf(a1.x); av[5] = (short)f2bf(a1.y);
            av[6] = (short)f2bf(a1.z); av[7] = (short)f2bf(a1.w);
        }
#pragma unroll
        for (int nt = 0; nt < NT; ++nt) {
            bf16x8 bv = *reinterpret_cast<bf16x8*>(
                &Wlds[(nt * 16 + lm) * LDK + s * 32 + kg * 8]);
            acc[nt] = __builtin_amdgcn_mfma_f32_16x16x32_bf16(av, bv, acc[nt], 0, 0, 0);
        }
    }

#pragma unroll
    for (int r = 0; r < 4; ++r) {
        int m = m0 + w * 16 + kg * 4 + r;
        if (m < N) {
            float sc = dinv[m] * FP8_S;
#pragma unroll
            for (int nt = 0; nt < NT; ++nt)
                G[(long)m * OF + nt * 16 + lm] = f2fp8(acc[nt][r] * sc);
        }
    }
}

// ---------------------------------------------------------------------------
// CSR aggregation — fp8 payload, NPW nodes per wave (lane groups of 64/NPW).
// Geometry per node group: WPE = OF/4 lanes/edge, EPW = (64/NPW)/WPE edges in
// parallel. NPW chosen so EPW==4 -> deg~32 fills the full 8-deep pipeline.
// f32 accumulate via HW cvt_pk; epilogue folds 1/S; optional bf16 output.
// ---------------------------------------------------------------------------
#define UNPK4(A, W)                                                        \
    {                                                                      \
        f32x2 _lo = __builtin_amdgcn_cvt_pk_f32_fp8((int)(W), false);      \
        f32x2 _hi = __builtin_amdgcn_cvt_pk_f32_fp8((int)(W), true);       \
        A.x += _lo[0]; A.y += _lo[1]; A.z += _hi[0]; A.w += _hi[1];        \
    }

template <int OF, int OSTRIDE, bool YBF16, int NPW>
__global__ __launch_bounds__(256) void k_agg(
    const int* __restrict__ row_off, const int* __restrict__ esrc,
    const uint* __restrict__ g,      // table row = OF/4 uints (OF fp8 bytes)
    const float* __restrict__ dinv, const float* __restrict__ b,
    void* __restrict__ y, int N)
{
    constexpr int LPN = 64 / NPW;    // lanes per node group
    constexpr int WPE = OF / 4;      // lanes per edge
    constexpr int EPW = LPN / WPE;   // edges in parallel per node
    const int lane = threadIdx.x & 63;
    const int grp = lane / LPN;      // node group within wave
    const int ll  = lane % LPN;
    const int q = ll % WPE;          // feature quad
    const int sub = ll / WPE;        // edge sub-slot
    const int wid = blockIdx.x * (blockDim.x >> 6) + (threadIdx.x >> 6);
    const int n = wid * NPW + grp;
    if (n >= N) return;
    const int start = row_off[n], end = row_off[n + 1];

    float4 ac[4];
#pragma unroll
    for (int u = 0; u < 4; ++u) ac[u] = make_float4(0.f, 0.f, 0.f, 0.f);

    int e = start + sub;
    for (; e + 7 * EPW < end; e += 8 * EPW) {
        int s0[4], s1[4];
#pragma unroll
        for (int u = 0; u < 4; ++u) s0[u] = esrc[e + u * EPW];
#pragma unroll
        for (int u = 0; u < 4; ++u) s1[u] = esrc[e + (4 + u) * EPW];
        uint w0[4], w1[4];
#pragma unroll
        for (int u = 0; u < 4; ++u) w0[u] = g[(long)s0[u] * WPE + q];
#pragma unroll
        for (int u = 0; u < 4; ++u) w1[u] = g[(long)s1[u] * WPE + q];
#pragma unroll
        for (int u = 0; u < 4; ++u) { UNPK4(ac[u], w0[u]); }
#pragma unroll
        for (int u = 0; u < 4; ++u) { UNPK4(ac[u], w1[u]); }
    }
    for (; e + 3 * EPW < end; e += 4 * EPW) {
        int s[4];
        uint w[4];
#pragma unroll
        for (int u = 0; u < 4; ++u) s[u] = esrc[e + u * EPW];
#pragma unroll
        for (int u = 0; u < 4; ++u) w[u] = g[(long)s[u] * WPE + q];
#pragma unroll
        for (int u = 0; u < 4; ++u) { UNPK4(ac[u], w[u]); }
    }
    for (; e < end; e += EPW) {
        uint w = g[(long)esrc[e] * WPE + q];
        UNPK4(ac[0], w);
    }
    float4 a;
    a.x = (ac[0].x + ac[1].x) + (ac[2].x + ac[3].x);
    a.y = (ac[0].y + ac[1].y) + (ac[2].y + ac[3].y);
    a.z = (ac[0].z + ac[1].z) + (ac[2].z + ac[3].z);
    a.w = (ac[0].w + ac[1].w) + (ac[2].w + ac[3].w);
#pragma unroll
    for (int m = WPE; m < LPN; m <<= 1) {   // group-local reduction
        a.x += __shfl_xor(a.x, m, 64);
        a.y += __shfl_xor(a.y, m, 64);
        a.z += __shfl_xor(a.z, m, 64);
        a.w += __shfl_xor(a.w, m, 64);
    }
    if (sub == 0) {
        uint sv = g[(long)n * WPE + q];   // self loop
        UNPK4(a, sv);
        float dvs = dinv[n] * (1.0f / FP8_S);
        float4 bb = *reinterpret_cast<const float4*>(&b[q * 4]);
        float4 o;
        o.x = fmaxf(fmaf(a.x, dvs, bb.x), 0.f);
        o.y = fmaxf(fmaf(a.y, dvs, bb.y), 0.f);
        o.z = fmaxf(fmaf(a.z, dvs, bb.z), 0.f);
        o.w = fmaxf(fmaf(a.w, dvs, bb.w), 0.f);
        if (YBF16) {
            ushort4 ob = {f2bf(o.x), f2bf(o.y), f2bf(o.z), f2bf(o.w)};
            *reinterpret_cast<ushort4*>((ushort*)y + (long)n * OSTRIDE + q * 4) = ob;
        } else {
            *reinterpret_cast<float4*>((float*)y + (long)n * OSTRIDE + q * 4) = o;
        }
    }
}

extern "C" void kernel_launch(void* const* d_in, const int* in_sizes, int n_in,
                              void* d_out, int out_size, void* d_ws, size_t ws_size,
                              hipStream_t stream) {
    const int*   nodes = (const int*)d_in[0];
    const int*   edges = (const int*)d_in[1];
    const float* emb   = (const float*)d_in[2];
    const float* W1    = (const float*)d_in[3];
    const float* b1    = (const float*)d_in[4];
    const float* W2    = (const float*)d_in[5];
    const float* b2    = (const float*)d_in[6];
    const float* W3    = (const float*)d_in[7];
    const float* b3    = (const float*)d_in[8];

    const int N = in_sizes[0];
    const int E = in_sizes[1] / 2;
    const int* src  = edges;
    const int* dstv = edges + E;
    const int NB = (N + BNODES - 1) >> BSH;   // 196 for N=100000

    char* ws = (char*)d_ws;
    size_t off = 0;
    auto alloc = [&](size_t bytes) {
        char* p = ws + off;
        off += (bytes + 255) & ~(size_t)255;
        return p;
    };
    float* dinv    = (float*)alloc((size_t)N * 4);
    int*   row_off = (int*)  alloc((size_t)(N + 1) * 4);
    int*   bcnt    = (int*)  alloc((size_t)(NB + 1) * 4);
    int*   boff    = (int*)  alloc((size_t)(NB + 1) * 4);
    int*   bcur    = (int*)  alloc((size_t)NB * 4);
    int*   esrc    = (int*)  alloc((size_t)E * 4);
    char*  shared_region = alloc((size_t)E * 4);   // pairs u32 (12.8MB) / G1 fp8 (6.4MB)
    uint*  pairs   = (uint*)shared_region;
    unsigned char* G1 = (unsigned char*)shared_region;   // [N][64] fp8
    unsigned char* G2 = (unsigned char*)alloc((size_t)N * 32);
    unsigned char* G3 = (unsigned char*)alloc((size_t)N * 16);
    ushort* Xb     = (ushort*)alloc((size_t)N * 64 * 2);  // bf16 activations
    ushort* Wh1 = (ushort*)alloc(16384 * 2);
    ushort* Wh2 = (ushort*)alloc(2048 * 2);
    ushort* Wh3 = (ushort*)alloc(512 * 2);
    float* out     = (float*)d_out;

    // --- CSR build + dinv + W prep ---
    constexpr int CH = 8192;
    constexpr int HB = 1024;              // histogram blocks in k_pre
    const int nch = (E + CH - 1) / CH;
    hipMemsetAsync(bcnt, 0, (size_t)NB * 4, stream);
    hipLaunchKernelGGL(k_pre, dim3(HB + 74), dim3(256), 0, stream,
                       dstv, bcnt, E, HB, W1, W2, W3, Wh1, Wh2, Wh3);
    hipLaunchKernelGGL(k_bscan,  dim3(1), dim3(1024), 0, stream, bcnt, boff, bcur, NB);
    hipLaunchKernelGGL((k_part<CH>), dim3(nch), dim3(256), 0, stream,
                       src, dstv, bcur, pairs, E, NB);
    hipLaunchKernelGGL(k_bucket, dim3(NB), dim3(1024), 0, stream,
                       pairs, boff, row_off, dinv, esrc, N, NB, E);

    const int gb  = (N + 63) / 64;
    const int ab1 = (N + 3) / 4;    // 4 nodes/block (NPW=1)
    const int ab2 = (N + 7) / 8;    // 8 nodes/block (NPW=2)
    const int ab3 = (N + 15) / 16;  // 16 nodes/block (NPW=4)

    // --- layer 1: 256 -> 64 ---  (G1 overwrites pairs; dead after k_bucket)
    hipLaunchKernelGGL((k_mfma<256, 64, false>), dim3(gb), dim3(256), 0, stream,
                       emb, 256, nodes, Wh1, dinv, G1, N);
    hipLaunchKernelGGL((k_agg<64, 64, true, 1>), dim3(ab1), dim3(256), 0, stream,
                       row_off, esrc, (const uint*)G1, dinv, b1, Xb, N);
    // --- layer 2: 64 -> 32 ---
    hipLaunchKernelGGL((k_mfma<64, 32, true>), dim3(gb), dim3(256), 0, stream,
                       Xb, 64, (const int*)nullptr, Wh2, dinv, G2, N);
    hipLaunchKernelGGL((k_agg<32, 64, true, 2>), dim3(ab2), dim3(256), 0, stream,
                       row_off, esrc, (const uint*)G2, dinv, b2, Xb, N);
    // --- layer 3: 32 -> 16 ---
    hipLaunchKernelGGL((k_mfma<32, 16, true>), dim3(gb), dim3(256), 0, stream,
                       Xb, 64, (const int*)nullptr, Wh3, dinv, G3, N);
    hipLaunchKernelGGL((k_agg<16, 16, false, 4>), dim3(ab3), dim3(256), 0, stream,
                       row_off, esrc, (const uint*)G3, dinv, b3, out, N);
}